// Round 13
// baseline (131.462 us; speedup 1.0000x reference)
//
#include <hip/hip_runtime.h>
#include <math.h>

// DynamicRouting: C=1024, K=64, H=512.
// Round-13: persistent blocks. grid=256 (1 block/CU), 4 capsules per block.
// Full-capsule LDS double-buffer (2 x 64 KB fp16): while capsule `cap` computes
// (MFMA proj + register-resident routing), capsule cap+1 streams HBM->reg->LDS
// with 2-deep chunk rolling. ONE barrier per capsule (was 8 per projection) --
// r12 evidence: enc streamed at only 1.4 TB/s (4.4x under ceiling) because
// loads were only outstanding in tiny windows between barriers.
// Verified pieces reused: staging swizzle + B-fragment Wp (r12), acc layout
// acc[i*4+j][r] = xh[k][g], k=i*16+(lane>>4)*4+r, g=wave*64+j*16+(lane&15) (r7-r12).

#define KC 64
#define HD 512
#define NT 512
#define CPB4 4

typedef _Float16 half8  __attribute__((ext_vector_type(8)));
typedef _Float16 half4v __attribute__((ext_vector_type(4)));
typedef float    f32x4  __attribute__((ext_vector_type(4)));

// ---- W (fp32 [g][h]) -> fp16 in B-fragment order (verified r12) ----
__launch_bounds__(256)
__global__ void cast_w_kernel(const float* __restrict__ W, _Float16* __restrict__ Wp) {
    int u    = blockIdx.x * 256 + threadIdx.x;    // 0..32767
    int lane = u & 63;
    int j    = (u >> 6) & 3;
    int ks   = (u >> 8) & 1;
    int hs   = (u >> 9) & 7;
    int wv   = (u >> 12) & 7;
    int g  = wv * 64 + j * 16 + (lane & 15);
    int h0 = hs * 64 + ks * 32 + (lane >> 4) * 8;
    const float4* src = reinterpret_cast<const float4*>(W + (size_t)g * HD + h0);
    float4 a = src[0], b = src[1];
    half8 h = { (_Float16)a.x, (_Float16)a.y, (_Float16)a.z, (_Float16)a.w,
                (_Float16)b.x, (_Float16)b.y, (_Float16)b.z, (_Float16)b.w };
    *reinterpret_cast<half8*>(Wp + (size_t)u * 8) = h;
}

// ---- persistent fused kernel: 1 block/CU, 4 capsules, capsule pipeline ----
__launch_bounds__(NT, 2)
__global__ void routing_kernel(const float* __restrict__ enc,
                               const _Float16* __restrict__ Wp,
                               float* __restrict__ out) {
    __shared__ _Float16 slab[2][8][8][64][8];   // 128 KB: [buf][hs][plane][row][e]
    __shared__ float chatL[HD];
    __shared__ float bvec[KC];
    __shared__ float dvec[KC];
    __shared__ float bpart[8][KC];
    __shared__ float red[8];
    __shared__ float s_alpha;

    const int tid  = threadIdx.x;
    const int lane = tid & 63;
    const int wave = tid >> 6;
    const int l15  = lane & 15, l4 = lane >> 4;
    const int cbase = blockIdx.x * CPB4;
    const _Float16* wbase = Wp + ((size_t)wave << 15) + (lane << 3);

    // staging geometry (verified r12)
    const int r0   = tid >> 4;                  // 0..31
    const int c40  = (tid & 15) << 2;           // 0..60
    const int ks_w = c40 >> 5;
    const int l4g  = (c40 >> 3) & 3;
    const int e0w  = c40 & 7;                   // 0 or 4
    const int prow = (l4g * 16 + (r0 & 15)) ^ (l4g << 1);
    const int p0   = (r0 >> 4) * 2 + ks_w;
    const int p1   = p0 + 4;
    const int plane_r = lane ^ ((lane >> 4) << 1);

    float4 ev[2][2];                            // 2-deep staging regs (static idx)
    half8  bf[2][8];                            // W frags, 2-deep (static idx)

    auto eload = [&](int cap, int hs, int sel) {
        const float* eb = enc + (size_t)(cbase + cap) * (KC * HD);
        ev[sel][0] = *reinterpret_cast<const float4*>(eb + (size_t)r0 * HD + hs * 64 + c40);
        ev[sel][1] = *reinterpret_cast<const float4*>(eb + (size_t)(r0 + 32) * HD + hs * 64 + c40);
    };
    auto ewrite = [&](int buf, int hs, int sel) {
        float4 v0 = ev[sel][0], v1 = ev[sel][1];
        half4v h0 = { (_Float16)v0.x, (_Float16)v0.y, (_Float16)v0.z, (_Float16)v0.w };
        half4v h1 = { (_Float16)v1.x, (_Float16)v1.y, (_Float16)v1.z, (_Float16)v1.w };
        *reinterpret_cast<half4v*>(&slab[buf][hs][p0][prow][e0w]) = h0;
        *reinterpret_cast<half4v*>(&slab[buf][hs][p1][prow][e0w]) = h1;
    };
    auto bload = [&](int hs, int sel) {
        #pragma unroll
        for (int q = 0; q < 8; ++q)
            bf[sel][q] = *reinterpret_cast<const half8*>(wbase + hs * 4096 + q * 512);
    };

    // ---- prologue: stage capsule 0 into buf 0 (2-deep rolling) ----
    eload(0, 0, 0);
    eload(0, 1, 1);
    #pragma unroll
    for (int q = 0; q < 8; ++q) {
        ewrite(0, q, q & 1);
        if (q + 2 < 8) eload(0, q + 2, q & 1);
    }

    f32x4 acc[16];

    for (int cap = 0; cap < CPB4; ++cap) {
        const int cur = cap & 1;
        const int nxt = cur ^ 1;
        const bool st = (cap < CPB4 - 1);

        __syncthreads();                        // slab[cur] fully staged

        #pragma unroll
        for (int i = 0; i < 16; ++i) acc[i] = (f32x4){0.f, 0.f, 0.f, 0.f};
        if (tid < KC) bvec[tid] = 0.0f;

        if (st) eload(cap + 1, 0, 0);
        bload(0, 0);

        // ---- projection (no intra barriers) + background staging of cap+1 ----
        #pragma unroll
        for (int hs = 0; hs < 8; ++hs) {
            if (hs < 7) bload(hs + 1, (hs + 1) & 1);
            if (st && hs < 7) eload(cap + 1, hs + 1, (hs + 1) & 1);
            #pragma unroll
            for (int ks = 0; ks < 2; ++ks) {
                half8 af[4];
                #pragma unroll
                for (int i = 0; i < 4; ++i)
                    af[i] = *reinterpret_cast<const half8*>(&slab[cur][hs][i * 2 + ks][plane_r][0]);
                #pragma unroll
                for (int i = 0; i < 4; ++i)
                    #pragma unroll
                    for (int j = 0; j < 4; ++j)
                        acc[i * 4 + j] = __builtin_amdgcn_mfma_f32_16x16x32_f16(
                            af[i], bf[hs & 1][ks * 4 + j], acc[i * 4 + j], 0, 0, 0);
            }
            if (st) ewrite(nxt, hs, hs & 1);    // write chunk hs (loaded 1 phase ago)
        }

        // ---- routing: 3 iterations, x_hat register-resident (verified r8-r12) ----
        for (int it = 0; it < 3; ++it) {
            if (it > 0) {
                if (wave == 0) {                // softmax over K=64
                    float v = bvec[lane];
                    float m = v;
                    #pragma unroll
                    for (int off = 32; off; off >>= 1) m = fmaxf(m, __shfl_xor(m, off));
                    float e = expf(v - m);
                    float s = e;
                    #pragma unroll
                    for (int off = 32; off; off >>= 1) s += __shfl_xor(s, off);
                    dvec[lane] = e / s;
                }
                __syncthreads();
            }

            float chv[4];
            #pragma unroll
            for (int j = 0; j < 4; ++j) chv[j] = 0.f;
            #pragma unroll
            for (int i = 0; i < 4; ++i)
                #pragma unroll
                for (int r = 0; r < 4; ++r) {
                    float dk = (it == 0) ? (1.0f / 64.0f) : dvec[i * 16 + l4 * 4 + r];
                    #pragma unroll
                    for (int j = 0; j < 4; ++j)
                        chv[j] += dk * acc[i * 4 + j][r];
                }
            #pragma unroll
            for (int j = 0; j < 4; ++j) {       // l4-reduce (4 k-chunks)
                chv[j] += __shfl_xor(chv[j], 16);
                chv[j] += __shfl_xor(chv[j], 32);
            }
            if (l4 == 0) {
                #pragma unroll
                for (int j = 0; j < 4; ++j)
                    chatL[wave * 64 + j * 16 + l15] = chv[j];
            }
            {
                float p = chv[0] * chv[0] + chv[1] * chv[1] + chv[2] * chv[2] + chv[3] * chv[3];
                #pragma unroll
                for (int off = 1; off <= 8; off <<= 1) p += __shfl_xor(p, off);
                if (lane == 0) red[wave] = p;
            }
            __syncthreads();
            if (tid == 0) {
                float n2 = red[0] + red[1] + red[2] + red[3] + red[4] + red[5] + red[6] + red[7];
                s_alpha = sqrtf(n2) / (1.0f + n2);
            }
            __syncthreads();

            if (it < 2) {
                #pragma unroll
                for (int i = 0; i < 4; ++i)
                    #pragma unroll
                    for (int r = 0; r < 4; ++r) {
                        float s = acc[i * 4 + 0][r] * chv[0]
                                + acc[i * 4 + 1][r] * chv[1]
                                + acc[i * 4 + 2][r] * chv[2]
                                + acc[i * 4 + 3][r] * chv[3];
                        #pragma unroll
                        for (int off = 1; off <= 8; off <<= 1) s += __shfl_xor(s, off);
                        if (l15 == 0) bpart[wave][i * 16 + l4 * 4 + r] = s;
                    }
                __syncthreads();
                if (tid < KC) {
                    float t = 0.f;
                    #pragma unroll
                    for (int w = 0; w < 8; ++w) t += bpart[w][tid];
                    bvec[tid] += s_alpha * t;
                }
                __syncthreads();
            } else {
                out[(size_t)(cbase + cap) * HD + tid] = s_alpha * chatL[tid];
            }
        }
    }
}

extern "C" void kernel_launch(void* const* d_in, const int* in_sizes, int n_in,
                              void* d_out, int out_size, void* d_ws, size_t ws_size,
                              hipStream_t stream) {
    const float* enc = (const float*)d_in[0];   // [1024, 64, 512] fp32
    const float* W   = (const float*)d_in[1];   // [512, 512] fp32
    float* out       = (float*)d_out;           // [1024, 512] fp32
    _Float16* Wp     = (_Float16*)d_ws;         // 512 KB, B-fragment order
    (void)in_sizes; (void)n_in; (void)ws_size; (void)out_size;

    cast_w_kernel<<<128, 256, 0, stream>>>(W, Wp);
    routing_kernel<<<256, NT, 0, stream>>>(enc, Wp, out);
}

// Round 14
// 130.382 us; speedup vs baseline: 1.0083x; 1.0083x over previous
//
#include <hip/hip_runtime.h>
#include <math.h>

// DynamicRouting: C=1024, K=64, H=512.
// Round-14 = round-13 persistent pipeline (grid=256, 4 capsules/block,
// full-capsule LDS dbuf, 1 barrier/capsule) with the SPILL FIXED:
//  - r13 evidence: VGPR_Count=128 (launch_bounds cap) vs ~180 live ->
//    scratch spills (WRITE_SIZE 2->74.7 MB, FETCH 71->208 MB), 131 us.
//  - fix: __launch_bounds__(NT, 1) (cap 512) + bf single-buffer (-32 VGPR).
// Verified pieces: staging swizzle + B-fragment Wp (r12), acc layout
// acc[i*4+j][r] = xh[k][g], k=i*16+(lane>>4)*4+r, g=wave*64+j*16+(lane&15).

#define KC 64
#define HD 512
#define NT 512
#define CPB4 4

typedef _Float16 half8  __attribute__((ext_vector_type(8)));
typedef _Float16 half4v __attribute__((ext_vector_type(4)));
typedef float    f32x4  __attribute__((ext_vector_type(4)));

// ---- W (fp32 [g][h]) -> fp16 in B-fragment order (verified r12) ----
__launch_bounds__(256)
__global__ void cast_w_kernel(const float* __restrict__ W, _Float16* __restrict__ Wp) {
    int u    = blockIdx.x * 256 + threadIdx.x;    // 0..32767
    int lane = u & 63;
    int j    = (u >> 6) & 3;
    int ks   = (u >> 8) & 1;
    int hs   = (u >> 9) & 7;
    int wv   = (u >> 12) & 7;
    int g  = wv * 64 + j * 16 + (lane & 15);
    int h0 = hs * 64 + ks * 32 + (lane >> 4) * 8;
    const float4* src = reinterpret_cast<const float4*>(W + (size_t)g * HD + h0);
    float4 a = src[0], b = src[1];
    half8 h = { (_Float16)a.x, (_Float16)a.y, (_Float16)a.z, (_Float16)a.w,
                (_Float16)b.x, (_Float16)b.y, (_Float16)b.z, (_Float16)b.w };
    *reinterpret_cast<half8*>(Wp + (size_t)u * 8) = h;
}

// ---- persistent fused kernel: 1 block/CU, 4 capsules, capsule pipeline ----
__launch_bounds__(NT, 1)   // cap 512 VGPR: ~160 live, NO spills (r13 lesson)
__global__ void routing_kernel(const float* __restrict__ enc,
                               const _Float16* __restrict__ Wp,
                               float* __restrict__ out) {
    __shared__ _Float16 slab[2][8][8][64][8];   // 128 KB: [buf][hs][plane][row][e]
    __shared__ float chatL[HD];
    __shared__ float bvec[KC];
    __shared__ float dvec[KC];
    __shared__ float bpart[8][KC];
    __shared__ float red[8];
    __shared__ float s_alpha;

    const int tid  = threadIdx.x;
    const int lane = tid & 63;
    const int wave = tid >> 6;
    const int l15  = lane & 15, l4 = lane >> 4;
    const int cbase = blockIdx.x * CPB4;
    const _Float16* wbase = Wp + ((size_t)wave << 15) + (lane << 3);

    // staging geometry (verified r12)
    const int r0   = tid >> 4;                  // 0..31
    const int c40  = (tid & 15) << 2;           // 0..60
    const int ks_w = c40 >> 5;
    const int l4g  = (c40 >> 3) & 3;
    const int e0w  = c40 & 7;                   // 0 or 4
    const int prow = (l4g * 16 + (r0 & 15)) ^ (l4g << 1);
    const int p0   = (r0 >> 4) * 2 + ks_w;
    const int p1   = p0 + 4;
    const int plane_r = lane ^ ((lane >> 4) << 1);

    float4 ev[2][2];                            // 2-deep staging regs (static idx)
    half8  bf[8];                               // W frags, single buffer

    auto eload = [&](int cap, int hs, int sel) {
        const float* eb = enc + (size_t)(cbase + cap) * (KC * HD);
        ev[sel][0] = *reinterpret_cast<const float4*>(eb + (size_t)r0 * HD + hs * 64 + c40);
        ev[sel][1] = *reinterpret_cast<const float4*>(eb + (size_t)(r0 + 32) * HD + hs * 64 + c40);
    };
    auto ewrite = [&](int buf, int hs, int sel) {
        float4 v0 = ev[sel][0], v1 = ev[sel][1];
        half4v h0 = { (_Float16)v0.x, (_Float16)v0.y, (_Float16)v0.z, (_Float16)v0.w };
        half4v h1 = { (_Float16)v1.x, (_Float16)v1.y, (_Float16)v1.z, (_Float16)v1.w };
        *reinterpret_cast<half4v*>(&slab[buf][hs][p0][prow][e0w]) = h0;
        *reinterpret_cast<half4v*>(&slab[buf][hs][p1][prow][e0w]) = h1;
    };
    auto bload = [&](int hs) {
        #pragma unroll
        for (int q = 0; q < 8; ++q)
            bf[q] = *reinterpret_cast<const half8*>(wbase + hs * 4096 + q * 512);
    };

    // ---- prologue: stage capsule 0 into buf 0 (2-deep rolling) ----
    eload(0, 0, 0);
    eload(0, 1, 1);
    #pragma unroll
    for (int q = 0; q < 8; ++q) {
        ewrite(0, q, q & 1);
        if (q + 2 < 8) eload(0, q + 2, q & 1);
    }

    f32x4 acc[16];

    for (int cap = 0; cap < CPB4; ++cap) {
        const int cur = cap & 1;
        const int nxt = cur ^ 1;
        const bool st = (cap < CPB4 - 1);

        __syncthreads();                        // slab[cur] fully staged

        #pragma unroll
        for (int i = 0; i < 16; ++i) acc[i] = (f32x4){0.f, 0.f, 0.f, 0.f};
        if (tid < KC) bvec[tid] = 0.0f;

        if (st) eload(cap + 1, 0, 0);

        // ---- projection (no intra barriers) + background staging of cap+1 ----
        #pragma unroll
        for (int hs = 0; hs < 8; ++hs) {
            if (st && hs < 7) eload(cap + 1, hs + 1, (hs + 1) & 1);
            bload(hs);
            #pragma unroll
            for (int ks = 0; ks < 2; ++ks) {
                half8 af[4];
                #pragma unroll
                for (int i = 0; i < 4; ++i)
                    af[i] = *reinterpret_cast<const half8*>(&slab[cur][hs][i * 2 + ks][plane_r][0]);
                #pragma unroll
                for (int i = 0; i < 4; ++i)
                    #pragma unroll
                    for (int j = 0; j < 4; ++j)
                        acc[i * 4 + j] = __builtin_amdgcn_mfma_f32_16x16x32_f16(
                            af[i], bf[ks * 4 + j], acc[i * 4 + j], 0, 0, 0);
            }
            if (st) ewrite(nxt, hs, hs & 1);    // write chunk hs (loaded 1 phase ago)
        }

        // ---- routing: 3 iterations, x_hat register-resident (verified r8-r13) ----
        for (int it = 0; it < 3; ++it) {
            if (it > 0) {
                if (wave == 0) {                // softmax over K=64
                    float v = bvec[lane];
                    float m = v;
                    #pragma unroll
                    for (int off = 32; off; off >>= 1) m = fmaxf(m, __shfl_xor(m, off));
                    float e = expf(v - m);
                    float s = e;
                    #pragma unroll
                    for (int off = 32; off; off >>= 1) s += __shfl_xor(s, off);
                    dvec[lane] = e / s;
                }
                __syncthreads();
            }

            float chv[4];
            #pragma unroll
            for (int j = 0; j < 4; ++j) chv[j] = 0.f;
            #pragma unroll
            for (int i = 0; i < 4; ++i)
                #pragma unroll
                for (int r = 0; r < 4; ++r) {
                    float dk = (it == 0) ? (1.0f / 64.0f) : dvec[i * 16 + l4 * 4 + r];
                    #pragma unroll
                    for (int j = 0; j < 4; ++j)
                        chv[j] += dk * acc[i * 4 + j][r];
                }
            #pragma unroll
            for (int j = 0; j < 4; ++j) {       // l4-reduce (4 k-chunks)
                chv[j] += __shfl_xor(chv[j], 16);
                chv[j] += __shfl_xor(chv[j], 32);
            }
            if (l4 == 0) {
                #pragma unroll
                for (int j = 0; j < 4; ++j)
                    chatL[wave * 64 + j * 16 + l15] = chv[j];
            }
            {
                float p = chv[0] * chv[0] + chv[1] * chv[1] + chv[2] * chv[2] + chv[3] * chv[3];
                #pragma unroll
                for (int off = 1; off <= 8; off <<= 1) p += __shfl_xor(p, off);
                if (lane == 0) red[wave] = p;
            }
            __syncthreads();
            if (tid == 0) {
                float n2 = red[0] + red[1] + red[2] + red[3] + red[4] + red[5] + red[6] + red[7];
                s_alpha = sqrtf(n2) / (1.0f + n2);
            }
            __syncthreads();

            if (it < 2) {
                #pragma unroll
                for (int i = 0; i < 4; ++i)
                    #pragma unroll
                    for (int r = 0; r < 4; ++r) {
                        float s = acc[i * 4 + 0][r] * chv[0]
                                + acc[i * 4 + 1][r] * chv[1]
                                + acc[i * 4 + 2][r] * chv[2]
                                + acc[i * 4 + 3][r] * chv[3];
                        #pragma unroll
                        for (int off = 1; off <= 8; off <<= 1) s += __shfl_xor(s, off);
                        if (l15 == 0) bpart[wave][i * 16 + l4 * 4 + r] = s;
                    }
                __syncthreads();
                if (tid < KC) {
                    float t = 0.f;
                    #pragma unroll
                    for (int w = 0; w < 8; ++w) t += bpart[w][tid];
                    bvec[tid] += s_alpha * t;
                }
                __syncthreads();
            } else {
                out[(size_t)(cbase + cap) * HD + tid] = s_alpha * chatL[tid];
            }
        }
    }
}

extern "C" void kernel_launch(void* const* d_in, const int* in_sizes, int n_in,
                              void* d_out, int out_size, void* d_ws, size_t ws_size,
                              hipStream_t stream) {
    const float* enc = (const float*)d_in[0];   // [1024, 64, 512] fp32
    const float* W   = (const float*)d_in[1];   // [512, 512] fp32
    float* out       = (float*)d_out;           // [1024, 512] fp32
    _Float16* Wp     = (_Float16*)d_ws;         // 512 KB, B-fragment order
    (void)in_sizes; (void)n_in; (void)ws_size; (void)out_size;

    cast_w_kernel<<<128, 256, 0, stream>>>(W, Wp);
    routing_kernel<<<256, NT, 0, stream>>>(enc, Wp, out);
}

// Round 15
// 81.195 us; speedup vs baseline: 1.6191x; 1.6058x over previous
//
#include <hip/hip_runtime.h>
#include <math.h>

// DynamicRouting: C=1024, K=64, H=512.
// Round-15 = r12 (81us, clean) + (1) 3-deep eload pipeline, (2) 1-barrier
// routing iterations with deferred-alpha + redundant per-wave reductions.
// r13/r14 lesson: persistent cap-loop kept ev[]/bf[] runtime-indexed ->
// scratch (rule #20). Here EVERYTHING is statically indexed (full unroll).
// Verified pieces: staging swizzle + B-fragment Wp (r12), acc layout
// acc[i*4+j][r] = xh[k][g], k=i*16+(lane>>4)*4+r, g=wave*64+j*16+(lane&15).
// Deferred alpha: bpart stores RAW dot(xh_k, chat); alpha applied next iter
// (b += alpha*dot), exactly reference math reordered.

#define KC 64
#define HD 512
#define NT 512

typedef _Float16 half8  __attribute__((ext_vector_type(8)));
typedef _Float16 half4v __attribute__((ext_vector_type(4)));
typedef float    f32x4  __attribute__((ext_vector_type(4)));

// ---- W (fp32 [g][h]) -> fp16 in B-fragment order (verified r12) ----
__launch_bounds__(256)
__global__ void cast_w_kernel(const float* __restrict__ W, _Float16* __restrict__ Wp) {
    int u    = blockIdx.x * 256 + threadIdx.x;    // 0..32767
    int lane = u & 63;
    int j    = (u >> 6) & 3;
    int ks   = (u >> 8) & 1;
    int hs   = (u >> 9) & 7;
    int wv   = (u >> 12) & 7;
    int g  = wv * 64 + j * 16 + (lane & 15);
    int h0 = hs * 64 + ks * 32 + (lane >> 4) * 8;
    const float4* src = reinterpret_cast<const float4*>(W + (size_t)g * HD + h0);
    float4 a = src[0], b = src[1];
    half8 h = { (_Float16)a.x, (_Float16)a.y, (_Float16)a.z, (_Float16)a.w,
                (_Float16)b.x, (_Float16)b.y, (_Float16)b.z, (_Float16)b.w };
    *reinterpret_cast<half8*>(Wp + (size_t)u * 8) = h;
}

// ---- fused proj + routing, one capsule per block ----
__launch_bounds__(NT, 1)
__global__ void routing_kernel(const float* __restrict__ enc,
                               const _Float16* __restrict__ Wp,
                               float* __restrict__ out) {
    __shared__ _Float16 slab[2][8][64][8];      // 16 KB dbuf, fragment order
    __shared__ float chatL[HD];                 // 2 KB
    __shared__ float bpart[2][8][KC];           // 4 KB raw-dot partials (dbuf)
    __shared__ float redp[2][8];                // ||chat||^2 partials (dbuf)

    const int tid  = threadIdx.x;
    const int lane = tid & 63;
    const int wave = tid >> 6;
    const int l15  = lane & 15, l4 = lane >> 4;
    const int c    = blockIdx.x;
    const float* ebase = enc + (size_t)c * (KC * HD);
    const _Float16* wbase = Wp + ((size_t)wave << 15) + (lane << 3);

    // staging geometry (verified r12)
    const int r0   = tid >> 4;                  // 0..31
    const int c40  = (tid & 15) << 2;           // 0..60
    const int ks_w = c40 >> 5;
    const int l4g  = (c40 >> 3) & 3;
    const int e0w  = c40 & 7;                   // 0 or 4
    const int prow = (l4g * 16 + (r0 & 15)) ^ (l4g << 1);
    const int p0   = (r0 >> 4) * 2 + ks_w;
    const int p1   = p0 + 4;
    const int plane_r = lane ^ ((lane >> 4) << 1);

    float4 ev[3][2];                            // 3-deep staging regs (static idx)
    half8  bf[2][8];                            // W frags dbuf (static idx)

    auto eload = [&](int hs, int slot) {
        ev[slot][0] = *reinterpret_cast<const float4*>(ebase + (size_t)r0 * HD + hs * 64 + c40);
        ev[slot][1] = *reinterpret_cast<const float4*>(ebase + (size_t)(r0 + 32) * HD + hs * 64 + c40);
    };
    auto ewrite = [&](int chunk, int slot) {    // chunk -> slab[chunk&1]
        float4 v0 = ev[slot][0], v1 = ev[slot][1];
        half4v h0 = { (_Float16)v0.x, (_Float16)v0.y, (_Float16)v0.z, (_Float16)v0.w };
        half4v h1 = { (_Float16)v1.x, (_Float16)v1.y, (_Float16)v1.z, (_Float16)v1.w };
        *reinterpret_cast<half4v*>(&slab[chunk & 1][p0][prow][e0w]) = h0;
        *reinterpret_cast<half4v*>(&slab[chunk & 1][p1][prow][e0w]) = h1;
    };
    auto bload = [&](int hs) {
        #pragma unroll
        for (int q = 0; q < 8; ++q)
            bf[hs & 1][q] = *reinterpret_cast<const half8*>(wbase + hs * 4096 + q * 512);
    };

    f32x4 acc[16];
    #pragma unroll
    for (int i = 0; i < 16; ++i) acc[i] = (f32x4){0.f, 0.f, 0.f, 0.f};

    // ---- prologue: 3 chunks in flight, chunk 0 into slab ----
    eload(0, 0); eload(1, 1); eload(2, 2);
    bload(0);
    ewrite(0, 0);                               // vmcnt exposed once per block

    // ---- projection: 8 phases, eload 3 ahead, ewrite 2-phase-old regs ----
    #pragma unroll
    for (int hs = 0; hs < 8; ++hs) {
        __syncthreads();                        // chunk hs visible in slab[hs&1]
        if (hs < 7) bload(hs + 1);
        if (hs < 5) eload(hs + 3, hs % 3);      // chunks 3..7
        #pragma unroll
        for (int ks = 0; ks < 2; ++ks) {
            half8 af[4];
            #pragma unroll
            for (int i = 0; i < 4; ++i)
                af[i] = *reinterpret_cast<const half8*>(&slab[hs & 1][i * 2 + ks][plane_r][0]);
            #pragma unroll
            for (int i = 0; i < 4; ++i)
                #pragma unroll
                for (int j = 0; j < 4; ++j)
                    acc[i * 4 + j] = __builtin_amdgcn_mfma_f32_16x16x32_f16(
                        af[i], bf[hs & 1][ks * 4 + j], acc[i * 4 + j], 0, 0, 0);
        }
        if (hs < 7) ewrite(hs + 1, (hs + 1) % 3);  // regs loaded 2 phases ago
    }

    // ---- routing: deferred-alpha, 1 barrier per iteration ----
    float breg = 0.0f;                          // b[k=lane], redundant per wave
    float chv[4];

    // helper: chat from dk values (dk provided per (i,r) pair by caller arrays)
    // iter 0: dk = 1/64
    {
        #pragma unroll
        for (int j = 0; j < 4; ++j) chv[j] = 0.f;
        #pragma unroll
        for (int i = 0; i < 4; ++i)
            #pragma unroll
            for (int r = 0; r < 4; ++r) {
                #pragma unroll
                for (int j = 0; j < 4; ++j)
                    chv[j] += (1.0f / 64.0f) * acc[i * 4 + j][r];
            }
        #pragma unroll
        for (int j = 0; j < 4; ++j) {
            chv[j] += __shfl_xor(chv[j], 16);
            chv[j] += __shfl_xor(chv[j], 32);
        }
        float p = chv[0] * chv[0] + chv[1] * chv[1] + chv[2] * chv[2] + chv[3] * chv[3];
        #pragma unroll
        for (int off = 1; off <= 8; off <<= 1) p += __shfl_xor(p, off);
        if (lane == 0) redp[0][wave] = p;
        #pragma unroll
        for (int i = 0; i < 4; ++i)
            #pragma unroll
            for (int r = 0; r < 4; ++r) {
                float s = acc[i * 4 + 0][r] * chv[0] + acc[i * 4 + 1][r] * chv[1]
                        + acc[i * 4 + 2][r] * chv[2] + acc[i * 4 + 3][r] * chv[3];
                #pragma unroll
                for (int off = 1; off <= 8; off <<= 1) s += __shfl_xor(s, off);
                if (l15 == 0) bpart[0][wave][i * 16 + l4 * 4 + r] = s;
            }
        __syncthreads();
    }

    // iters 1,2: read parity (it-1)&1, write parity it&1
    #pragma unroll
    for (int it = 1; it < 3; ++it) {
        const int rp = (it - 1) & 1, wp = it & 1;
        // redundant per-wave: n2 -> alpha -> b update -> softmax -> dk
        float n2 = 0.f;
        #pragma unroll
        for (int w = 0; w < 8; ++w) n2 += redp[rp][w];
        float alpha = sqrtf(n2) / (1.0f + n2);
        float dot = 0.f;
        #pragma unroll
        for (int w = 0; w < 8; ++w) dot += bpart[rp][w][lane];
        breg += alpha * dot;
        // in-wave softmax over k=lane
        float m = breg;
        #pragma unroll
        for (int off = 32; off; off >>= 1) m = fmaxf(m, __shfl_xor(m, off));
        float e = expf(breg - m);
        float se = e;
        #pragma unroll
        for (int off = 32; off; off >>= 1) se += __shfl_xor(se, off);
        float dl = e / se;                      // d[k=lane]
        // chat with dk = shfl(dl, i*16+l4*4+r)
        #pragma unroll
        for (int j = 0; j < 4; ++j) chv[j] = 0.f;
        #pragma unroll
        for (int i = 0; i < 4; ++i)
            #pragma unroll
            for (int r = 0; r < 4; ++r) {
                float dk = __shfl(dl, i * 16 + l4 * 4 + r);
                #pragma unroll
                for (int j = 0; j < 4; ++j)
                    chv[j] += dk * acc[i * 4 + j][r];
            }
        #pragma unroll
        for (int j = 0; j < 4; ++j) {
            chv[j] += __shfl_xor(chv[j], 16);
            chv[j] += __shfl_xor(chv[j], 32);
        }
        float p = chv[0] * chv[0] + chv[1] * chv[1] + chv[2] * chv[2] + chv[3] * chv[3];
        #pragma unroll
        for (int off = 1; off <= 8; off <<= 1) p += __shfl_xor(p, off);
        if (lane == 0) redp[wp][wave] = p;

        if (it < 2) {
            #pragma unroll
            for (int i = 0; i < 4; ++i)
                #pragma unroll
                for (int r = 0; r < 4; ++r) {
                    float s = acc[i * 4 + 0][r] * chv[0] + acc[i * 4 + 1][r] * chv[1]
                            + acc[i * 4 + 2][r] * chv[2] + acc[i * 4 + 3][r] * chv[3];
                    #pragma unroll
                    for (int off = 1; off <= 8; off <<= 1) s += __shfl_xor(s, off);
                    if (l15 == 0) bpart[wp][wave][i * 16 + l4 * 4 + r] = s;
                }
            __syncthreads();
        } else {
            // final: publish chat, then scale by alpha2 after barrier
            if (l4 == 0) {
                #pragma unroll
                for (int j = 0; j < 4; ++j)
                    chatL[wave * 64 + j * 16 + l15] = chv[j];
            }
            __syncthreads();
            float n2f = 0.f;
            #pragma unroll
            for (int w = 0; w < 8; ++w) n2f += redp[wp][w];
            float alphaf = sqrtf(n2f) / (1.0f + n2f);
            out[(size_t)c * HD + tid] = alphaf * chatL[tid];
        }
    }
}

extern "C" void kernel_launch(void* const* d_in, const int* in_sizes, int n_in,
                              void* d_out, int out_size, void* d_ws, size_t ws_size,
                              hipStream_t stream) {
    const float* enc = (const float*)d_in[0];   // [1024, 64, 512] fp32
    const float* W   = (const float*)d_in[1];   // [512, 512] fp32
    float* out       = (float*)d_out;           // [1024, 512] fp32
    _Float16* Wp     = (_Float16*)d_ws;         // 512 KB, B-fragment order
    (void)in_sizes; (void)n_in; (void)ws_size; (void)out_size;

    cast_w_kernel<<<128, 256, 0, stream>>>(W, Wp);
    routing_kernel<<<1024, NT, 0, stream>>>(enc, Wp, out);
}